// Round 1
// baseline (246.323 us; speedup 1.0000x reference)
//
#include <hip/hip_runtime.h>

// LowRankGDN: out[n,c,p] = x[n,c,p] * rsqrt( beta_r[c] + sum_r A_r[c,r] * T[n,r,p] )
//   T[n,r,p] = sum_c A_r[c,r] * x[n,c,p]^2
// Shapes: x [8,192,256,256] f32, beta [192], A [192,8]. Output f32 same shape as x.

#define N_IMG 8
#define C_CH 192
#define R_RK 8
#define HW 65536            // 256*256
#define PIX_PER_BLOCK 512   // 256 threads * 2 pixels
#define BLOCKS_PER_IMG (HW / PIX_PER_BLOCK)   // 128

#define PEDESTAL_F 1.4551915228366852e-11f    // 2^-36
#define BOUND_A_F 3.814697265625e-06f         // 2^-18 = sqrt(pedestal)
#define BOUND_BETA_F 1.0000072759311364e-03f  // sqrt(1e-6 + 2^-36)

__global__ __launch_bounds__(256) void lrgdn_kernel(
    const float* __restrict__ x,
    const float* __restrict__ beta,
    const float* __restrict__ A,
    float* __restrict__ out)
{
    __shared__ float sA[C_CH][R_RK];   // reparametrized A
    __shared__ float sB[C_CH];         // reparametrized beta

    const int tid = threadIdx.x;

    // Reparametrize params into LDS (tiny: 192*8 + 192 floats)
    for (int i = tid; i < C_CH * R_RK; i += 256) {
        float a = A[i];
        a = fmaxf(a, BOUND_A_F);
        sA[i / R_RK][i % R_RK] = a * a - PEDESTAL_F;
    }
    for (int i = tid; i < C_CH; i += 256) {
        float b = fmaxf(beta[i], BOUND_BETA_F);
        sB[i] = b * b - PEDESTAL_F;
    }
    __syncthreads();

    const int blk = blockIdx.x;
    const int n  = blk / BLOCKS_PER_IMG;
    const int p0 = (blk % BLOCKS_PER_IMG) * PIX_PER_BLOCK;

    const float* xn = x   + n * (C_CH * HW) + p0;
    float*       on = out + n * (C_CH * HW) + p0;
    const int px = tid * 2;   // this thread's pixel pair within the tile

    float T0[R_RK], T1[R_RK];
#pragma unroll
    for (int r = 0; r < R_RK; ++r) { T0[r] = 0.f; T1[r] = 0.f; }

    // ---- pass 1: accumulate T[r] = sum_c A_r[c,r] * x^2 ----
#pragma unroll 4
    for (int c = 0; c < C_CH; ++c) {
        float2 v = *reinterpret_cast<const float2*>(xn + c * HW + px);
        float s0 = v.x * v.x;
        float s1 = v.y * v.y;
#pragma unroll
        for (int r = 0; r < R_RK; ++r) {
            float a = sA[c][r];            // uniform address -> LDS broadcast
            T0[r] = fmaf(s0, a, T0[r]);
            T1[r] = fmaf(s1, a, T1[r]);
        }
    }

    // ---- pass 2: denom = beta_r + sum_r A_r[c,r]*T[r]; out = x * rsqrt(denom) ----
#pragma unroll 4
    for (int c = 0; c < C_CH; ++c) {
        float2 v = *reinterpret_cast<const float2*>(xn + c * HW + px);
        float d0 = sB[c];
        float d1 = d0;
#pragma unroll
        for (int r = 0; r < R_RK; ++r) {
            float a = sA[c][r];
            d0 = fmaf(a, T0[r], d0);
            d1 = fmaf(a, T1[r], d1);
        }
        float2 o;
        o.x = v.x * __builtin_amdgcn_rsqf(d0);
        o.y = v.y * __builtin_amdgcn_rsqf(d1);
        *reinterpret_cast<float2*>(on + c * HW + px) = o;
    }
}

extern "C" void kernel_launch(void* const* d_in, const int* in_sizes, int n_in,
                              void* d_out, int out_size, void* d_ws, size_t ws_size,
                              hipStream_t stream) {
    const float* x    = (const float*)d_in[0];
    const float* beta = (const float*)d_in[1];
    const float* A    = (const float*)d_in[2];
    float* out = (float*)d_out;

    dim3 grid(N_IMG * BLOCKS_PER_IMG);   // 1024 blocks
    dim3 block(256);
    hipLaunchKernelGGL(lrgdn_kernel, grid, block, 0, stream, x, beta, A, out);
}

// Round 2
// 211.612 us; speedup vs baseline: 1.1640x; 1.1640x over previous
//
#include <hip/hip_runtime.h>

// LowRankGDN: out[n,c,p] = x[n,c,p] * rsqrt( beta_r[c] + sum_r A_r[c,r] * T[n,r,p] )
//   T[n,r,p] = sum_c A_r[c,r] * x[n,c,p]^2
// Shapes: x [8,192,256,256] f32, beta [192], A [192,8]. Output f32 same shape as x.
//
// R2: 1 pixel/thread -> 2048 blocks (8 blocks/CU, 32 waves/CU = 100% occupancy
// target) to hide HBM latency via TLP. unroll 8 for MLP. Nontemporal stores to
// keep the write stream from evicting x in L3 (pass-2 re-read is L3-hit, R1
// FETCH_SIZE == one x read).

#define N_IMG 8
#define C_CH 192
#define R_RK 8
#define HW 65536            // 256*256
#define PIX_PER_BLOCK 256   // 256 threads * 1 pixel
#define BLOCKS_PER_IMG (HW / PIX_PER_BLOCK)   // 256

#define PEDESTAL_F 1.4551915228366852e-11f    // 2^-36
#define BOUND_A_F 3.814697265625e-06f         // 2^-18 = sqrt(pedestal)
#define BOUND_BETA_F 1.0000072759311364e-03f  // sqrt(1e-6 + 2^-36)

__global__ __launch_bounds__(256) void lrgdn_kernel(
    const float* __restrict__ x,
    const float* __restrict__ beta,
    const float* __restrict__ A,
    float* __restrict__ out)
{
    __shared__ float sA[C_CH][R_RK];   // reparametrized A
    __shared__ float sB[C_CH];         // reparametrized beta

    const int tid = threadIdx.x;

    // Reparametrize params into LDS (tiny: 192*8 + 192 floats)
    for (int i = tid; i < C_CH * R_RK; i += 256) {
        float a = A[i];
        a = fmaxf(a, BOUND_A_F);
        sA[i / R_RK][i % R_RK] = a * a - PEDESTAL_F;
    }
    for (int i = tid; i < C_CH; i += 256) {
        float b = fmaxf(beta[i], BOUND_BETA_F);
        sB[i] = b * b - PEDESTAL_F;
    }
    __syncthreads();

    const int blk = blockIdx.x;
    const int n  = blk / BLOCKS_PER_IMG;
    const int p0 = (blk % BLOCKS_PER_IMG) * PIX_PER_BLOCK;

    const float* xn = x   + n * (C_CH * HW) + p0 + tid;
    float*       on = out + n * (C_CH * HW) + p0 + tid;

    float T[R_RK];
#pragma unroll
    for (int r = 0; r < R_RK; ++r) T[r] = 0.f;

    // ---- pass 1: T[r] = sum_c A_r[c,r] * x^2 ----
#pragma unroll 8
    for (int c = 0; c < C_CH; ++c) {
        float v = xn[c * HW];
        float s = v * v;
#pragma unroll
        for (int r = 0; r < R_RK; ++r) {
            T[r] = fmaf(s, sA[c][r], T[r]);   // uniform LDS addr -> broadcast
        }
    }

    // ---- pass 2: denom = beta_r + sum_r A_r[c,r]*T[r]; out = x * rsqrt(denom) ----
#pragma unroll 8
    for (int c = 0; c < C_CH; ++c) {
        float v = xn[c * HW];
        float d = sB[c];
#pragma unroll
        for (int r = 0; r < R_RK; ++r) {
            d = fmaf(sA[c][r], T[r], d);
        }
        float o = v * __builtin_amdgcn_rsqf(d);
        __builtin_nontemporal_store(o, on + c * HW);
    }
}

extern "C" void kernel_launch(void* const* d_in, const int* in_sizes, int n_in,
                              void* d_out, int out_size, void* d_ws, size_t ws_size,
                              hipStream_t stream) {
    const float* x    = (const float*)d_in[0];
    const float* beta = (const float*)d_in[1];
    const float* A    = (const float*)d_in[2];
    float* out = (float*)d_out;

    dim3 grid(N_IMG * BLOCKS_PER_IMG);   // 2048 blocks
    dim3 block(256);
    hipLaunchKernelGGL(lrgdn_kernel, grid, block, 0, stream, x, beta, A, out);
}

// Round 3
// 198.183 us; speedup vs baseline: 1.2429x; 1.0678x over previous
//
#include <hip/hip_runtime.h>

// LowRankGDN: out[n,c,p] = x[n,c,p] * rsqrt( beta_r[c] + sum_r A_r[c,r] * T[n,r,p] )
//   T[n,r,p] = sum_c A_r[c,r] * x[n,c,p]^2
// Shapes: x [8,192,256,256] f32, beta [192], A [192,8]. Output f32, same shape.
//
// R3: single-pass. R2 showed pass-2 re-read is L3-hit (FETCH=402MB) but the
// combined fabric traffic (402 HBM rd + 402 L3 rd + 402 wr = 1.2GB @ 5.7TB/s)
// was the ceiling. Now: x lives in REGISTERS. Block = 64 pixels x 4 channel
// slices (256 thr); each thread holds x[48] in VGPRs, accumulates partial
// T[8], cross-slice reduce via LDS (sT[4][8][64]: conflict-free), then
// computes outputs from registers. Global traffic = one read + one write.

#define N_IMG 8
#define C_CH 192
#define R_RK 8
#define HW 65536              // 256*256
#define PX_PER_BLOCK 64
#define CSLICES 4
#define CPT (C_CH / CSLICES)  // 48 channels per thread
#define BLOCKS_PER_IMG (HW / PX_PER_BLOCK)   // 1024

#define PEDESTAL_F 1.4551915228366852e-11f    // 2^-36
#define BOUND_A_F 3.814697265625e-06f         // 2^-18 = sqrt(pedestal)
#define BOUND_BETA_F 1.0000072759311364e-03f  // sqrt(1e-6 + 2^-36)

__global__ __launch_bounds__(256) void lrgdn_kernel(
    const float* __restrict__ x,
    const float* __restrict__ beta,
    const float* __restrict__ A,
    float* __restrict__ out)
{
    __shared__ float sA[C_CH][R_RK];            // reparametrized A
    __shared__ float sB[C_CH];                  // reparametrized beta
    __shared__ float sT[CSLICES][R_RK][PX_PER_BLOCK];  // partial T

    const int tid = threadIdx.x;

    // Reparametrize params into LDS (tiny)
    for (int i = tid; i < C_CH * R_RK; i += 256) {
        float a = A[i];
        a = fmaxf(a, BOUND_A_F);
        sA[i / R_RK][i % R_RK] = a * a - PEDESTAL_F;
    }
    for (int i = tid; i < C_CH; i += 256) {
        float b = fmaxf(beta[i], BOUND_BETA_F);
        sB[i] = b * b - PEDESTAL_F;
    }
    __syncthreads();

    const int blk = blockIdx.x;
    const int n  = blk / BLOCKS_PER_IMG;
    const int p0 = (blk % BLOCKS_PER_IMG) * PX_PER_BLOCK;

    const int px = tid & 63;        // wave = 64 consecutive pixels -> coalesced
    const int cs = tid >> 6;        // channel slice (uniform per wave)
    const int c0 = cs * CPT;

    const float* xn = x   + n * (C_CH * HW) + p0 + px;
    float*       on = out + n * (C_CH * HW) + p0 + px;

    // ---- load this thread's 48 channels into registers, accumulate T ----
    float xr[CPT];
    float T[R_RK];
#pragma unroll
    for (int r = 0; r < R_RK; ++r) T[r] = 0.f;

#pragma unroll
    for (int i = 0; i < CPT; ++i) {
        xr[i] = xn[(c0 + i) * HW];
    }
#pragma unroll
    for (int i = 0; i < CPT; ++i) {
        float v = xr[i];
        float s = v * v;
#pragma unroll
        for (int r = 0; r < R_RK; ++r) {
            T[r] = fmaf(s, sA[c0 + i][r], T[r]);   // uniform LDS addr -> broadcast
        }
    }

    // ---- cross-slice reduce of T via LDS ----
#pragma unroll
    for (int r = 0; r < R_RK; ++r) {
        sT[cs][r][px] = T[r];       // lanes write consecutive px -> conflict-free
    }
    __syncthreads();

    float Tf[R_RK];
#pragma unroll
    for (int r = 0; r < R_RK; ++r) {
        Tf[r] = (sT[0][r][px] + sT[1][r][px]) + (sT[2][r][px] + sT[3][r][px]);
    }

    // ---- epilogue: denom + rsqrt + store, all from registers ----
#pragma unroll
    for (int i = 0; i < CPT; ++i) {
        int c = c0 + i;
        float d = sB[c];
#pragma unroll
        for (int r = 0; r < R_RK; ++r) {
            d = fmaf(sA[c][r], Tf[r], d);
        }
        float o = xr[i] * __builtin_amdgcn_rsqf(d);
        __builtin_nontemporal_store(o, on + c * HW);
    }
}

extern "C" void kernel_launch(void* const* d_in, const int* in_sizes, int n_in,
                              void* d_out, int out_size, void* d_ws, size_t ws_size,
                              hipStream_t stream) {
    const float* x    = (const float*)d_in[0];
    const float* beta = (const float*)d_in[1];
    const float* A    = (const float*)d_in[2];
    float* out = (float*)d_out;

    dim3 grid(N_IMG * BLOCKS_PER_IMG);   // 8192 blocks
    dim3 block(256);
    hipLaunchKernelGGL(lrgdn_kernel, grid, block, 0, stream, x, beta, A, out);
}

// Round 4
// 167.130 us; speedup vs baseline: 1.4738x; 1.1858x over previous
//
#include <hip/hip_runtime.h>

// LowRankGDN: out[n,c,p] = x[n,c,p] * rsqrt( beta_r[c] + sum_r A_r[c,r] * T[n,r,p] )
//   T[n,r,p] = sum_c A_r[c,r] * x[n,c,p]^2
// Shapes: x [8,192,256,256] f32, beta [192], A [192,8]. Output f32, same shape.
//
// R4: single-pass (x in registers), but occupancy-first. R3's xr[48] cost
// VGPR=104 -> 4 waves/SIMD -> 21% occupancy, latency-bound at 3 TB/s.
// Now: 512-thr block = 64 px x 8 channel-slices, 24 channels/thread.
// __launch_bounds__(512,8) pins VGPR<=64 -> 8 waves/SIMD.
// Traffic stays minimal: one x read + one out write.

#define N_IMG 8
#define C_CH 192
#define R_RK 8
#define HW 65536              // 256*256
#define PX_PER_BLOCK 64
#define CSLICES 8
#define CPT (C_CH / CSLICES)  // 24 channels per thread
#define NTHR (PX_PER_BLOCK * CSLICES)         // 512
#define BLOCKS_PER_IMG (HW / PX_PER_BLOCK)    // 1024

#define PEDESTAL_F 1.4551915228366852e-11f    // 2^-36
#define BOUND_A_F 3.814697265625e-06f         // 2^-18 = sqrt(pedestal)
#define BOUND_BETA_F 1.0000072759311364e-03f  // sqrt(1e-6 + 2^-36)

__global__ __launch_bounds__(NTHR, 8) void lrgdn_kernel(
    const float* __restrict__ x,
    const float* __restrict__ beta,
    const float* __restrict__ A,
    float* __restrict__ out)
{
    __shared__ float sA[C_CH][R_RK];                   // reparametrized A (6 KB)
    __shared__ float sB[C_CH];                         // reparametrized beta
    __shared__ float sT[CSLICES][R_RK][PX_PER_BLOCK];  // partial T (16 KB)

    const int tid = threadIdx.x;

    // Reparametrize params into LDS (tiny)
    for (int i = tid; i < C_CH * R_RK; i += NTHR) {
        float a = A[i];
        a = fmaxf(a, BOUND_A_F);
        sA[i / R_RK][i % R_RK] = a * a - PEDESTAL_F;
    }
    for (int i = tid; i < C_CH; i += NTHR) {
        float b = fmaxf(beta[i], BOUND_BETA_F);
        sB[i] = b * b - PEDESTAL_F;
    }
    __syncthreads();

    const int blk = blockIdx.x;
    const int n  = blk / BLOCKS_PER_IMG;
    const int p0 = (blk % BLOCKS_PER_IMG) * PX_PER_BLOCK;

    const int px = tid & 63;        // wave = 64 consecutive pixels -> coalesced
    const int cs = tid >> 6;        // channel slice (uniform per wave)
    const int c0 = cs * CPT;

    const float* xn = x   + n * (C_CH * HW) + p0 + px + c0 * HW;
    float*       on = out + n * (C_CH * HW) + p0 + px + c0 * HW;

    // ---- load this thread's 24 channels into registers, accumulate T ----
    float xr[CPT];
    float T[R_RK];
#pragma unroll
    for (int r = 0; r < R_RK; ++r) T[r] = 0.f;

#pragma unroll
    for (int i = 0; i < CPT; ++i) {
        xr[i] = xn[i * HW];
    }
#pragma unroll
    for (int i = 0; i < CPT; ++i) {
        float v = xr[i];
        float s = v * v;
#pragma unroll
        for (int r = 0; r < R_RK; ++r) {
            T[r] = fmaf(s, sA[c0 + i][r], T[r]);   // uniform LDS addr -> broadcast
        }
    }

    // ---- cross-slice reduce of T via LDS ----
#pragma unroll
    for (int r = 0; r < R_RK; ++r) {
        sT[cs][r][px] = T[r];       // lanes write consecutive px -> conflict-free
    }
    __syncthreads();

    float Tf[R_RK];
#pragma unroll
    for (int r = 0; r < R_RK; ++r) {
        float t01 = sT[0][r][px] + sT[1][r][px];
        float t23 = sT[2][r][px] + sT[3][r][px];
        float t45 = sT[4][r][px] + sT[5][r][px];
        float t67 = sT[6][r][px] + sT[7][r][px];
        Tf[r] = (t01 + t23) + (t45 + t67);
    }

    // ---- epilogue: denom + rsqrt + store, all from registers ----
#pragma unroll
    for (int i = 0; i < CPT; ++i) {
        int c = c0 + i;
        float d = sB[c];
#pragma unroll
        for (int r = 0; r < R_RK; ++r) {
            d = fmaf(sA[c][r], Tf[r], d);
        }
        float o = xr[i] * __builtin_amdgcn_rsqf(d);
        __builtin_nontemporal_store(o, on + i * HW);
    }
}

extern "C" void kernel_launch(void* const* d_in, const int* in_sizes, int n_in,
                              void* d_out, int out_size, void* d_ws, size_t ws_size,
                              hipStream_t stream) {
    const float* x    = (const float*)d_in[0];
    const float* beta = (const float*)d_in[1];
    const float* A    = (const float*)d_in[2];
    float* out = (float*)d_out;

    dim3 grid(N_IMG * BLOCKS_PER_IMG);   // 8192 blocks
    dim3 block(NTHR);                    // 512
    hipLaunchKernelGGL(lrgdn_kernel, grid, block, 0, stream, x, beta, A, out);
}